// Round 6
// baseline (457.556 us; speedup 1.0000x reference)
//
#include <hip/hip_runtime.h>
#include <hip/hip_bf16.h>
#include <math.h>

#define NN   16
#define C_   128
#define HH   128
#define WW   128
#define CHID 32
#define NTILES 64   // one tile per output y-pair

#define BCHUNK 33792  // one B chunk: 4 rows * 132 px * 32 ci * 2B

typedef short bf16x8 __attribute__((ext_vector_type(8)));
typedef float f32x4  __attribute__((ext_vector_type(4)));

__device__ inline void glds16(const void* g, void* l) {
    __builtin_amdgcn_global_load_lds(
        (const __attribute__((address_space(1))) unsigned int*)g,
        (__attribute__((address_space(3))) unsigned int*)l, 16, 0, 0);
}

__device__ inline unsigned short f2bf(float f) {
    __hip_bfloat16 h = __float2bfloat16(f);
    return *reinterpret_cast<unsigned short*>(&h);
}

// ---------------------------------------------------------------------------
// Pack conv weights into MFMA-A fragment-linear layout (bf16):
// wl[conv][kk 9][ck 4][cot 8][lane 64][8] ; value = W[co][ci][ky][kx]
// with co = cot*16 + (l&15), ci = ck*32 + (l>>4)*8 + j, kk = ky*3+kx.
__global__ __launch_bounds__(64) void pack_w_k(
    const float* __restrict__ w1, const float* __restrict__ w2,
    unsigned short* __restrict__ wl)
{
    const int b = blockIdx.x;                 // conv*288 + kk*32 + ck*8 + cot
    const int conv = b / 288, rem = b % 288;
    const int kk = rem / 32, ck = (rem % 32) / 8, cot = rem % 8;
    const int l = threadIdx.x;
    const int co  = cot * 16 + (l & 15);
    const int ci0 = ck * 32 + (l >> 4) * 8;
    const float* W = conv ? w2 : w1;
    union { unsigned short u[8]; uint4 v; } pk;
#pragma unroll
    for (int j = 0; j < 8; ++j)
        pk.u[j] = f2bf(W[(size_t)(co * C_ + ci0 + j) * 9 + kk]);
    unsigned short* dst = wl + (size_t)conv * 147456 +
        ((((size_t)kk * 4 + ck) * 8 + cot) * 64 + l) * 8;
    *reinterpret_cast<uint4*>(dst) = pk.v;
}

// ---------------------------------------------------------------------------
// fp32 NCHW -> bf16 chunked-NHWC: xb[n][y][ck4][x128][ci32]
// LDS tile swizzled: row x holds ci-octet s at slot s ^ h(x), h(x)=(x>>2)&7.
__global__ __launch_bounds__(256) void to_cnhwc_k(
    const float* __restrict__ x, unsigned short* __restrict__ xb)
{
    __shared__ unsigned short s_t[128][136];   // row 272B = 17 x 16B slots
    const int y = blockIdx.x, n = blockIdx.y, t = threadIdx.x;

#pragma unroll
    for (int p = 0; p < 16; ++p) {
        int fi = p * 256 + t;                  // float4 index over [ci][x/4]
        int ci = fi >> 5, x0 = (fi & 31) * 4;
        float4 v = *reinterpret_cast<const float4*>(
            x + (((size_t)(n * C_ + ci) * HH) + y) * WW + x0);
        const int slot = ((ci >> 3) ^ ((x0 >> 2) & 7)) * 8 + (ci & 7);
        s_t[x0 + 0][slot] = f2bf(v.x);
        s_t[x0 + 1][slot] = f2bf(v.y);
        s_t[x0 + 2][slot] = f2bf(v.z);
        s_t[x0 + 3][slot] = f2bf(v.w);
    }
    __syncthreads();
    unsigned short* dstbase = xb + ((size_t)(n * HH + y)) * 16384;
#pragma unroll
    for (int p = 0; p < 8; ++p) {
        int o = p * 256 + t;                   // 16B unit: 2048 total
        int ck = o >> 9, u = o & 511;
        int xc = u >> 2, q = u & 3;
        int k = ck * 4 + q;                    // ci-octet pair index (16B)
        uint4 v = *reinterpret_cast<const uint4*>(
            &s_t[xc][(k ^ ((xc >> 2) & 7)) * 8]);
        *reinterpret_cast<uint4*>(dstbase + (size_t)ck * 4096 + xc * 32 + q * 8) = v;
    }
}

// ---------------------------------------------------------------------------
// Implicit-GEMM 3x3 conv. Block: 128 c_out x (2 rows x 128 x) at (n, yp).
// 8 waves: w -> wco = w>>2, wy = (w>>1)&1, wxh = w&1 ; wave tile 64co x 64x.
// Pipeline regime: __launch_bounds__(512,4) -> VGPR cap 128, 2 blocks/CU.
// Double-buffered B chunks, stage(ck+1) issued before compute(ck).
// Per kk-iteration: A-frags loaded JIT, next iteration's B-frags prefetched
// into registers before the 16 MFMAs (LDS latency hidden under MFMA).
// B tile slot-swizzled: row xi's 16B slot s holds ci-sub s ^ ((xi>>1)&3).
// CONV==1: out bf16 chunked-NHWC + PReLU (LDS-repacked 16B stores).
// CONV==2: out fp32 NCHW + avg-pool partials.
template<int CONV>
__global__ __launch_bounds__(512, 4) void conv_mfma_k(
    const unsigned short* __restrict__ inb,   // bf16 chunked-NHWC
    const unsigned short* __restrict__ wl,    // this conv's packed frags
    const float* __restrict__ bias,
    const float* __restrict__ prelu_a,
    unsigned short* __restrict__ outb,        // CONV==1
    float* __restrict__ outf,                 // CONV==2
    float* __restrict__ partial)              // CONV==2
{
    __shared__ char  smem[2 * BCHUNK];        // B dbuf; repack overlays later
    __shared__ float s_part[8][64];

    const int tid = threadIdx.x;
    const int l = tid & 63, w = tid >> 6;
    const int wco = w >> 2, wy = (w >> 1) & 1, wxh = w & 1;
    const int lg = l >> 4, l15 = l & 15;
    const int yp = blockIdx.x, n = blockIdx.z;
    const int y0 = yp * 2;

    const f32x4 fz = {0.f, 0.f, 0.f, 0.f};
    f32x4 acc[4][4];
#pragma unroll
    for (int m = 0; m < 4; ++m)
#pragma unroll
        for (int nf = 0; nf < 4; ++nf) acc[m][nf] = fz;

    const bf16x8* wv = reinterpret_cast<const bf16x8*>(wl);
    const uint4 z4 = {0u, 0u, 0u, 0u};

    // stage B chunk `ck` into buffer `sb`
    auto stage = [&](int ck, char* sb) {
        const int r = w >> 1, xh = w & 1;
        const int ygl = y0 - 1 + r;
        if (ygl < 0 || ygl >= HH) {
            int t2 = xh * 64 + l;
            for (int i = t2; i < 528; i += 128)
                *reinterpret_cast<uint4*>(sb + r * 8448 + i * 16) = z4;
        } else {
            if (xh == 0 && l < 8) {            // zero pad cols xi=0, xi=129
                int col = (l < 4) ? 0 : 129, q = l & 3;
                *reinterpret_cast<uint4*>(sb + r * 8448 + col * 64 + q * 16) = z4;
            }
            size_t rowbase = (((size_t)(n * HH + ygl)) * 4 + ck) * 8192;
#pragma unroll
            for (int i = 0; i < 4; ++i) {
                // lane l -> pixel p, LDS slot (l&3); pre-swizzle the SOURCE
                // so that slot s_l holds ci-sub s_l ^ f(1+p).
                const int p  = xh * 64 + i * 16 + (l >> 2);
                const int sd = (l & 3) ^ (((1 + p) >> 1) & 3);
                const char* g = (const char*)inb + rowbase + (size_t)p * 64 + sd * 16;
                glds16(g, sb + r * 8448 + (1 + xh * 64 + i * 16) * 64);
            }
        }
    };

    stage(0, smem);
    __syncthreads();

    for (int ck = 0; ck < 4; ++ck) {
        char* buf = smem + (ck & 1) * BCHUNK;
        // ---- issue next chunk's staging first (overlaps with compute) ----
        if (ck < 3) stage(ck + 1, smem + ((ck + 1) & 1) * BCHUNK);

        // read the 4 B fragments for iteration kk of this chunk
        auto rdB = [&](int kk, bf16x8* b) {
            const int ky = kk / 3, kx = kk % 3;
            const int rrow = wy + ky;
#pragma unroll
            for (int nf = 0; nf < 4; ++nf) {
                int xi = wxh * 64 + nf * 16 + l15 + kx;
                int slot = lg ^ ((xi >> 1) & 3);
                b[nf] = *reinterpret_cast<const bf16x8*>(
                    buf + rrow * 8448 + xi * 64 + slot * 16);
            }
        };

        // ---- compute: 9 shifted GEMMs, B prefetched one kk ahead ----
        bf16x8 b_cur[4], b_nxt[4];
        rdB(0, b_cur);
#pragma unroll
        for (int kk = 0; kk < 9; ++kk) {
            bf16x8 a[4];
#pragma unroll
            for (int m = 0; m < 4; ++m)
                a[m] = wv[(((size_t)kk * 4 + ck) * 8 + wco * 4 + m) * 64 + l];
            if (kk < 8) rdB(kk + 1, b_nxt);
#pragma unroll
            for (int nf = 0; nf < 4; ++nf)
#pragma unroll
                for (int m = 0; m < 4; ++m)
                    acc[m][nf] = __builtin_amdgcn_mfma_f32_16x16x32_bf16(
                        a[m], b_cur[nf], acc[m][nf], 0, 0, 0);
            if (kk < 8) {
#pragma unroll
                for (int nf = 0; nf < 4; ++nf) b_cur[nf] = b_nxt[nf];
            }
        }
        __syncthreads();   // stage(ck+1) landed; both buffers consistent
    }

    // ---- epilogue ----
    const int ybase = y0 + wy;
    if (CONV == 1) {
        const float a1 = *prelu_a;
        unsigned short (*s_rp)[136] = reinterpret_cast<unsigned short (*)[136]>(smem);
        // Repack via LDS so each global store is a full 16B line segment.
        for (int r = 0; r < 2; ++r) {
            if (wy == r) {
#pragma unroll
                for (int m = 0; m < 4; ++m) {
                    const int co0 = wco * 64 + m * 16 + lg * 4;
#pragma unroll
                    for (int nf = 0; nf < 4; ++nf) {
                        const int xc = wxh * 64 + nf * 16 + l15;
                        union { unsigned short u[4]; uint2 v; } pk;
#pragma unroll
                        for (int jj = 0; jj < 4; ++jj) {
                            float f = acc[m][nf][jj] + bias[co0 + jj];
                            f = (f >= 0.f) ? f : a1 * f;
                            pk.u[jj] = f2bf(f);
                        }
                        *reinterpret_cast<uint2*>(&s_rp[xc][co0]) = pk.v;
                    }
                }
            }
            __syncthreads();
            const int y = y0 + r;
#pragma unroll
            for (int p = 0; p < 4; ++p) {
                int u = p * 512 + tid;         // 2048 16B units: [xc][k]
                int xc = u >> 4, k = u & 15;
                uint4 v = *reinterpret_cast<const uint4*>(&s_rp[xc][k * 8]);
                *reinterpret_cast<uint4*>(outb +
                    (((size_t)(n * HH + y)) * 4 + (k >> 2)) * 4096 +
                    xc * 32 + (k & 3) * 8) = v;
            }
            __syncthreads();
        }
    } else {
        float ps[4][4];
#pragma unroll
        for (int m = 0; m < 4; ++m)
#pragma unroll
            for (int jj = 0; jj < 4; ++jj) ps[m][jj] = 0.f;
#pragma unroll
        for (int m = 0; m < 4; ++m) {
            const int co0 = wco * 64 + m * 16 + lg * 4;
#pragma unroll
            for (int nf = 0; nf < 4; ++nf) {
                const int xc = wxh * 64 + nf * 16 + l15;
#pragma unroll
                for (int jj = 0; jj < 4; ++jj) {
                    float f = acc[m][nf][jj] + bias[co0 + jj];
                    outf[(((size_t)(n * C_ + co0 + jj)) * HH + ybase) * WW + xc] = f;
                    ps[m][jj] += f;
                }
            }
        }
#pragma unroll
        for (int m = 0; m < 4; ++m)
#pragma unroll
            for (int jj = 0; jj < 4; ++jj) {
                float s = ps[m][jj];
                s += __shfl_xor(s, 1); s += __shfl_xor(s, 2);
                s += __shfl_xor(s, 4); s += __shfl_xor(s, 8);
                ps[m][jj] = s;
            }
        if (l15 == 0) {
#pragma unroll
            for (int m = 0; m < 4; ++m)
#pragma unroll
                for (int jj = 0; jj < 4; ++jj)
                    s_part[w][m * 16 + lg * 4 + jj] = ps[m][jj];
        }
        __syncthreads();
        if (tid < C_) {
            const int half = tid >> 6;
            float s = 0.f;
#pragma unroll
            for (int w2 = 0; w2 < 4; ++w2) s += s_part[half * 4 + w2][tid & 63];
            partial[((size_t)(n * C_ + tid)) * NTILES + yp] = s;
        }
    }
}

// ---------------------------------------------------------------------------
// One block per sample: reduce partials -> x1, expert MLP, sigmoid gate.
__global__ __launch_bounds__(C_) void adapter_k(
    const float* __restrict__ partial, const int* __restrict__ intensity,
    const float* __restrict__ aW1, const float* __restrict__ ab1,
    const float* __restrict__ aW2, const float* __restrict__ ab2,
    float* __restrict__ sig)
{
    __shared__ float sx[C_];
    __shared__ float sa[CHID];
    const int n = blockIdx.x, c = threadIdx.x;

    float s = 0.f;
    for (int t = 0; t < NTILES; ++t)
        s += partial[(size_t)(n * C_ + c) * NTILES + t];
    sx[c] = s * (1.f / (float)(HH * WW));
    __syncthreads();

    const int idx = intensity[n] - 1;
    if (c < CHID) {
        float a = ab1[idx * CHID + c];
        const float* wrow = aW1 + (size_t)(idx * CHID + c) * C_;
        for (int k = 0; k < C_; ++k) a = fmaf(wrow[k], sx[k], a);
        sa[c] = fmaxf(a, 0.f);
    }
    __syncthreads();

    float g = ab2[idx * C_ + c];
    const float* w2row = aW2 + (size_t)(idx * C_ + c) * CHID;
#pragma unroll
    for (int k = 0; k < CHID; ++k) g = fmaf(w2row[k], sa[k], g);
    sig[n * C_ + c] = 1.f / (1.f + expf(-g));
}

// ---------------------------------------------------------------------------
// out = prelu(h * sig[n,c] + x, p2), in-place on d_out.
__global__ __launch_bounds__(256) void epilogue_k(
    const float* __restrict__ x, const float* __restrict__ sig,
    const float* __restrict__ prelu_a, float* __restrict__ out, int total4)
{
    const float a = *prelu_a;
    const int stride = gridDim.x * blockDim.x;
    for (int i = blockIdx.x * blockDim.x + threadIdx.x; i < total4; i += stride) {
        const int nc = (i * 4) >> 14;
        const float s = sig[nc];
        float4 h4 = ((const float4*)out)[i];
        float4 x4 = ((const float4*)x)[i];
        float4 v;
        v.x = h4.x * s + x4.x;  v.x = (v.x >= 0.f) ? v.x : a * v.x;
        v.y = h4.y * s + x4.y;  v.y = (v.y >= 0.f) ? v.y : a * v.y;
        v.z = h4.z * s + x4.z;  v.z = (v.z >= 0.f) ? v.z : a * v.z;
        v.w = h4.w * s + x4.w;  v.w = (v.w >= 0.f) ? v.w : a * v.w;
        ((float4*)out)[i] = v;
    }
}

// ---------------------------------------------------------------------------
extern "C" void kernel_launch(void* const* d_in, const int* in_sizes, int n_in,
                              void* d_out, int out_size, void* d_ws, size_t ws_size,
                              hipStream_t stream)
{
    const float* x         = (const float*)d_in[0];
    const int*   intensity = (const int*)  d_in[1];
    const float* w1        = (const float*)d_in[2];
    const float* b1        = (const float*)d_in[3];
    const float* p1        = (const float*)d_in[4];
    const float* w2        = (const float*)d_in[5];
    const float* b2        = (const float*)d_in[6];
    const float* aW1       = (const float*)d_in[7];
    const float* ab1       = (const float*)d_in[8];
    const float* aW2       = (const float*)d_in[9];
    const float* ab2       = (const float*)d_in[10];
    const float* p2        = (const float*)d_in[11];
    float* out = (float*)d_out;

    // xb (bf16 chunked-NHWC of x) borrows the front half of d_out: it is dead
    // before conv2 overwrites d_out with h.
    unsigned short* xb = (unsigned short*)d_out;              // 67.1 MB

    // workspace: h1b (bf16) | wl (packed weights) | partial | sig
    unsigned short* h1b = (unsigned short*)d_ws;              // 67.1 MB
    unsigned short* wl  = (unsigned short*)((char*)d_ws + (size_t)33554432 * 2);
    float* partial = (float*)((char*)wl + (size_t)294912 * 2);
    float* sig     = partial + (size_t)NN * C_ * NTILES;

    pack_w_k<<<dim3(576), dim3(64), 0, stream>>>(w1, w2, wl);
    to_cnhwc_k<<<dim3(HH, NN), dim3(256), 0, stream>>>(x, xb);

    conv_mfma_k<1><<<dim3(NTILES, 1, NN), dim3(512), 0, stream>>>(
        xb, wl, b1, p1, h1b, nullptr, nullptr);
    conv_mfma_k<2><<<dim3(NTILES, 1, NN), dim3(512), 0, stream>>>(
        h1b, wl + (size_t)147456, b2, nullptr, nullptr, out, partial);

    adapter_k<<<dim3(NN), dim3(C_), 0, stream>>>(
        partial, intensity, aW1, ab1, aW2, ab2, sig);

    const int total4 = NN * C_ * HH * WW / 4;
    epilogue_k<<<dim3(2048), dim3(256), 0, stream>>>(x, sig, p2, out, total4);
}

// Round 7
// 302.296 us; speedup vs baseline: 1.5136x; 1.5136x over previous
//
#include <hip/hip_runtime.h>
#include <hip/hip_bf16.h>
#include <math.h>

#define NN   16
#define C_   128
#define HH   128
#define WW   128
#define CHID 32
#define NTILES 64     // one tile per output y-pair

#define ROWB 4224     // LDS bytes per staged row: 132 px * 32B (16 ci bf16)
#define HC   16896    // half-chunk buffer: 4 rows * ROWB

typedef short bf16x8 __attribute__((ext_vector_type(8)));
typedef float f32x16 __attribute__((ext_vector_type(16)));

__device__ inline void glds16(const void* g, void* l) {
    __builtin_amdgcn_global_load_lds(
        (const __attribute__((address_space(1))) unsigned int*)g,
        (__attribute__((address_space(3))) unsigned int*)l, 16, 0, 0);
}

__device__ inline unsigned short f2bf(float f) {
    __hip_bfloat16 h = __float2bfloat16(f);
    return *reinterpret_cast<unsigned short*>(&h);
}

// ---------------------------------------------------------------------------
// Pack conv weights into 32x32x16 MFMA-A fragment-linear layout (bf16):
// wl[conv][kk 9][ck8 8][cot 4][lane 64][8] ; value = W[co][ci][kk]
// with co = cot*32 + (l&31), ci = ck8*16 + (l>>5)*8 + j.  (verified R5)
__global__ __launch_bounds__(64) void pack_w_k(
    const float* __restrict__ w1, const float* __restrict__ w2,
    unsigned short* __restrict__ wl)
{
    const int b = blockIdx.x;                 // conv*288 + kk*32 + ck8*4 + cot
    const int conv = b / 288, rem = b % 288;
    const int kk = rem / 32, ck8 = (rem % 32) / 4, cot = rem % 4;
    const int l = threadIdx.x;
    const int co  = cot * 32 + (l & 31);
    const int ci0 = ck8 * 16 + (l >> 5) * 8;
    const float* W = conv ? w2 : w1;
    union { unsigned short u[8]; uint4 v; } pk;
#pragma unroll
    for (int j = 0; j < 8; ++j)
        pk.u[j] = f2bf(W[(size_t)(co * C_ + ci0 + j) * 9 + kk]);
    unsigned short* dst = wl + (size_t)conv * 147456 +
        ((((size_t)kk * 8 + ck8) * 4 + cot) * 64 + l) * 8;
    *reinterpret_cast<uint4*>(dst) = pk.v;
}

// ---------------------------------------------------------------------------
// fp32 NCHW -> bf16 ci16-chunked-NHWC: xb[n][y][ck8 8][x128][ci16]
// LDS tile: row x holds ci-octet s at slot s ^ ((x>>2)&7).
__global__ __launch_bounds__(256) void to_cnhwc_k(
    const float* __restrict__ x, unsigned short* __restrict__ xb)
{
    __shared__ unsigned short s_t[128][136];   // row 272B = 17 x 16B slots
    const int y = blockIdx.x, n = blockIdx.y, t = threadIdx.x;

#pragma unroll
    for (int p = 0; p < 16; ++p) {
        int fi = p * 256 + t;                  // float4 index over [ci][x/4]
        int ci = fi >> 5, x0 = (fi & 31) * 4;
        float4 v = *reinterpret_cast<const float4*>(
            x + (((size_t)(n * C_ + ci) * HH) + y) * WW + x0);
        const int slot = ((ci >> 3) ^ ((x0 >> 2) & 7)) * 8 + (ci & 7);
        s_t[x0 + 0][slot] = f2bf(v.x);
        s_t[x0 + 1][slot] = f2bf(v.y);
        s_t[x0 + 2][slot] = f2bf(v.z);
        s_t[x0 + 3][slot] = f2bf(v.w);
    }
    __syncthreads();
    unsigned short* dstbase = xb + ((size_t)(n * HH + y)) * 16384;
#pragma unroll
    for (int p = 0; p < 8; ++p) {
        int o = p * 256 + t;                   // 16B unit: 2048 total
        int ck8 = o >> 8, u = o & 255;
        int xc = u >> 1, q = u & 1;
        int oct = ck8 * 2 + q;                 // ci-octet 0..15
        uint4 v = *reinterpret_cast<const uint4*>(
            &s_t[xc][(oct ^ ((xc >> 2) & 7)) * 8]);
        *reinterpret_cast<uint4*>(dstbase + (size_t)ck8 * 2048 + xc * 16 + q * 8) = v;
    }
}

// ---------------------------------------------------------------------------
// Implicit-GEMM 3x3 conv, 32x32x16 MFMA, ci16 half-chunks, double-buffered.
// Block: 128co x (2y x 128px) at (n, yp). 8 waves: wco2 x wy2 x wxh2;
// wave tile 64co x 64px (2x2 frags of 32x32). 8 half-chunks of 16 ci;
// stage(hc+1) issued before compute(hc) -> barrier drain hidden under MFMA.
// LDS rows 132px x 32B, frag reads contiguous 1KB -> no swizzle needed.
// Total regs ~= 64 AGPR acc + ~50 arch -> 4 waves/SIMD; LDS 34.8KB -> 4 blk/CU.
// MODE 0: bf16 NHWC out + PReLU (conv1). MODE 1: bf16 NHWC out + partials
// (conv2, big-ws path). MODE 2: fp32 NCHW out + partials (conv2 fallback).
template<int MODE>
__global__ __launch_bounds__(512) void conv_mfma_k(
    const unsigned short* __restrict__ inb,   // bf16 ci16-chunked-NHWC
    const unsigned short* __restrict__ wl,    // this conv's packed frags
    const float* __restrict__ bias,
    const float* __restrict__ prelu_a,
    unsigned short* __restrict__ outb,        // MODE 0/1
    float* __restrict__ outf,                 // MODE 2
    float* __restrict__ partial)              // MODE 1/2
{
    __shared__ char  smem[34816];             // 2*HC (33792) / repack (34816)
    __shared__ float s_part[8][64];

    const int tid = threadIdx.x;
    const int l = tid & 63, w = tid >> 6;
    const int wco = w >> 2, wy = (w >> 1) & 1, wxh = w & 1;
    const int l31 = l & 31, sel = l >> 5;
    const int yp = blockIdx.x, n = blockIdx.z;
    const int y0 = yp * 2;

    f32x16 acc[2][2];
#pragma unroll
    for (int m = 0; m < 2; ++m)
#pragma unroll
        for (int nf = 0; nf < 2; ++nf)
#pragma unroll
            for (int r = 0; r < 16; ++r) acc[m][nf][r] = 0.f;

    const bf16x8* wv = reinterpret_cast<const bf16x8*>(wl);
    const uint4 z4 = {0u, 0u, 0u, 0u};

    // stage half-chunk hc (16 ci) into buffer buf. Wave (r=w>>1, xh=w&1)
    // stages the 2KB half-body of row r; tid<16 writes the px0/px129 pads.
    auto stage = [&](int hc, char* buf) {
        if (tid < 16) {
            const int r = tid >> 2, px = ((tid >> 1) & 1) ? 129 : 0, sl = tid & 1;
            *reinterpret_cast<uint4*>(buf + r * ROWB + px * 32 + sl * 16) = z4;
        }
        const int r = w >> 1, xh = w & 1;
        const int ygl = y0 - 1 + r;
        char* dst0 = buf + r * ROWB + 32 + xh * 2048;
        if (ygl < 0 || ygl >= HH) {
            *reinterpret_cast<uint4*>(dst0 + l * 16) = z4;
            *reinterpret_cast<uint4*>(dst0 + 1024 + l * 16) = z4;
        } else {
            const char* src0 = (const char*)inb +
                (((size_t)(n * HH + ygl)) * 8 + hc) * 4096 +
                (size_t)xh * 2048 + (l >> 1) * 32 + (l & 1) * 16;
            glds16(src0, dst0);
            glds16(src0 + 1024, dst0 + 1024);
        }
    };

    stage(0, smem);
    __syncthreads();

    for (int hc = 0; hc < 8; ++hc) {
        char* buf = smem + (hc & 1) * HC;
        if (hc < 7) stage(hc + 1, smem + ((hc + 1) & 1) * HC);

        // ---- compute: 9 shifted K=16 GEMM steps; A prefetched one kk ahead
        bf16x8 a_cur[2];
#pragma unroll
        for (int m = 0; m < 2; ++m)
            a_cur[m] = wv[((0 * 8 + hc) * 4 + wco * 2 + m) * 64 + l];

#pragma unroll
        for (int kk = 0; kk < 9; ++kk) {
            const int ky = kk / 3, kx = kk % 3;
            bf16x8 a_nxt[2];
            if (kk < 8) {
#pragma unroll
                for (int m = 0; m < 2; ++m)
                    a_nxt[m] = wv[(((kk + 1) * 8 + hc) * 4 + wco * 2 + m) * 64 + l];
            }
            const int rrow = wy + ky;
            bf16x8 b[2];
#pragma unroll
            for (int nf = 0; nf < 2; ++nf) {
                const int xi = wxh * 64 + nf * 32 + l31 + kx;
                b[nf] = *reinterpret_cast<const bf16x8*>(
                    buf + rrow * ROWB + xi * 32 + sel * 16);
            }
#pragma unroll
            for (int nf = 0; nf < 2; ++nf)
#pragma unroll
                for (int m = 0; m < 2; ++m)
                    acc[m][nf] = __builtin_amdgcn_mfma_f32_32x32x16_bf16(
                        a_cur[m], b[nf], acc[m][nf], 0, 0, 0);
            if (kk < 8) {
#pragma unroll
                for (int m = 0; m < 2; ++m) a_cur[m] = a_nxt[m];
            }
        }
        __syncthreads();   // stage(hc+1) landed; both buffers consistent
    }

    // ---- epilogue ----
    // 32x32 C/D layout (verified): col px = l31, row co = (reg&3)+8*(reg>>2)+4*sel
    const int ybase = y0 + wy;
    if (MODE == 0 || MODE == 1) {
        const float a1 = (MODE == 0) ? *prelu_a : 0.f;
        float ps[2][16];
        if (MODE == 1) {
#pragma unroll
            for (int m = 0; m < 2; ++m)
#pragma unroll
                for (int r = 0; r < 16; ++r) ps[m][r] = 0.f;
        }
        unsigned short (*s_rp)[136] = reinterpret_cast<unsigned short (*)[136]>(smem);
        for (int r = 0; r < 2; ++r) {
            if (wy == r) {
#pragma unroll
                for (int m = 0; m < 2; ++m)
#pragma unroll
                    for (int nf = 0; nf < 2; ++nf) {
                        const int xc = wxh * 64 + nf * 32 + l31;
#pragma unroll
                        for (int q = 0; q < 4; ++q) {
                            const int co0 = wco * 64 + m * 32 + q * 8 + sel * 4;
                            union { unsigned short u[4]; uint2 v; } pk;
#pragma unroll
                            for (int jj = 0; jj < 4; ++jj) {
                                float f = acc[m][nf][q * 4 + jj] + bias[co0 + jj];
                                if (MODE == 0) f = (f >= 0.f) ? f : a1 * f;
                                else           ps[m][q * 4 + jj] += f;
                                pk.u[jj] = f2bf(f);
                            }
                            *reinterpret_cast<uint2*>(&s_rp[xc][co0]) = pk.v;
                        }
                    }
            }
            __syncthreads();
            const int y = y0 + r;
#pragma unroll
            for (int p = 0; p < 4; ++p) {
                int u = p * 512 + tid;         // 2048 16B units: [xc][k16]
                int xc = u >> 4, k = u & 15;
                uint4 v = *reinterpret_cast<const uint4*>(&s_rp[xc][k * 8]);
                *reinterpret_cast<uint4*>(outb +
                    (((size_t)(n * HH + y)) * 8 + (k >> 1)) * 2048 +
                    xc * 16 + (k & 1) * 8) = v;
            }
            __syncthreads();
        }
        if (MODE == 1) {
#pragma unroll
            for (int m = 0; m < 2; ++m)
#pragma unroll
                for (int r = 0; r < 16; ++r) {
                    float s = ps[m][r];
                    s += __shfl_xor(s, 1);  s += __shfl_xor(s, 2);
                    s += __shfl_xor(s, 4);  s += __shfl_xor(s, 8);
                    s += __shfl_xor(s, 16);
                    ps[m][r] = s;
                }
            if (l31 == 0) {
#pragma unroll
                for (int m = 0; m < 2; ++m)
#pragma unroll
                    for (int q = 0; q < 4; ++q)
#pragma unroll
                        for (int jj = 0; jj < 4; ++jj)
                            s_part[w][m * 32 + q * 8 + sel * 4 + jj] = ps[m][q * 4 + jj];
            }
            __syncthreads();
            if (tid < C_) {
                const int half = tid >> 6;
                float s = 0.f;
#pragma unroll
                for (int w2 = 0; w2 < 4; ++w2) s += s_part[half * 4 + w2][tid & 63];
                partial[((size_t)(n * C_ + tid)) * NTILES + yp] = s;
            }
        }
    } else {
        float ps[2][16];
#pragma unroll
        for (int m = 0; m < 2; ++m)
#pragma unroll
            for (int r = 0; r < 16; ++r) ps[m][r] = 0.f;
#pragma unroll
        for (int m = 0; m < 2; ++m)
#pragma unroll
            for (int nf = 0; nf < 2; ++nf) {
                const int x = wxh * 64 + nf * 32 + l31;
#pragma unroll
                for (int q = 0; q < 4; ++q) {
                    const int co0 = wco * 64 + m * 32 + q * 8 + sel * 4;
#pragma unroll
                    for (int jj = 0; jj < 4; ++jj) {
                        float f = acc[m][nf][q * 4 + jj] + bias[co0 + jj];
                        outf[(((size_t)(n * C_ + co0 + jj)) * HH + ybase) * WW + x] = f;
                        ps[m][q * 4 + jj] += f;
                    }
                }
            }
#pragma unroll
        for (int m = 0; m < 2; ++m)
#pragma unroll
            for (int r = 0; r < 16; ++r) {
                float s = ps[m][r];
                s += __shfl_xor(s, 1);  s += __shfl_xor(s, 2);
                s += __shfl_xor(s, 4);  s += __shfl_xor(s, 8);
                s += __shfl_xor(s, 16);
                ps[m][r] = s;
            }
        if (l31 == 0) {
#pragma unroll
            for (int m = 0; m < 2; ++m)
#pragma unroll
                for (int q = 0; q < 4; ++q)
#pragma unroll
                    for (int jj = 0; jj < 4; ++jj)
                        s_part[w][m * 32 + q * 8 + sel * 4 + jj] = ps[m][q * 4 + jj];
        }
        __syncthreads();
        if (tid < C_) {
            const int half = tid >> 6;
            float s = 0.f;
#pragma unroll
            for (int w2 = 0; w2 < 4; ++w2) s += s_part[half * 4 + w2][tid & 63];
            partial[((size_t)(n * C_ + tid)) * NTILES + yp] = s;
        }
    }
}

// ---------------------------------------------------------------------------
// One block per sample: reduce partials -> x1, expert MLP, sigmoid gate.
__global__ __launch_bounds__(C_) void adapter_k(
    const float* __restrict__ partial, const int* __restrict__ intensity,
    const float* __restrict__ aW1, const float* __restrict__ ab1,
    const float* __restrict__ aW2, const float* __restrict__ ab2,
    float* __restrict__ sig)
{
    __shared__ float sx[C_];
    __shared__ float sa[CHID];
    const int n = blockIdx.x, c = threadIdx.x;

    float s = 0.f;
    for (int t = 0; t < NTILES; ++t)
        s += partial[(size_t)(n * C_ + c) * NTILES + t];
    sx[c] = s * (1.f / (float)(HH * WW));
    __syncthreads();

    const int idx = intensity[n] - 1;
    if (c < CHID) {
        float a = ab1[idx * CHID + c];
        const float* wrow = aW1 + (size_t)(idx * CHID + c) * C_;
        for (int k = 0; k < C_; ++k) a = fmaf(wrow[k], sx[k], a);
        sa[c] = fmaxf(a, 0.f);
    }
    __syncthreads();

    float g = ab2[idx * C_ + c];
    const float* w2row = aW2 + (size_t)(idx * C_ + c) * CHID;
#pragma unroll
    for (int k = 0; k < CHID; ++k) g = fmaf(w2row[k], sa[k], g);
    sig[n * C_ + c] = 1.f / (1.f + expf(-g));
}

// ---------------------------------------------------------------------------
// Big-ws epilogue: h (bf16 ci16-NHWC) + x (fp32 NCHW) -> out fp32 NCHW.
// out = prelu(h*sig + x, p2). One block per (y, n).
__global__ __launch_bounds__(256) void epilogue_bf16_k(
    const unsigned short* __restrict__ h2b, const float* __restrict__ x,
    const float* __restrict__ sig, const float* __restrict__ prelu_a,
    float* __restrict__ out)
{
    __shared__ unsigned short s_h[128][136];
    const int y = blockIdx.x, n = blockIdx.y, t = threadIdx.x;
    const float a = *prelu_a;
    const unsigned short* slab = h2b + ((size_t)(n * HH + y)) * 16384;

#pragma unroll
    for (int p = 0; p < 8; ++p) {
        int o = p * 256 + t;
        int ck8 = o >> 8, u = o & 255;
        int xc = u >> 1, q = u & 1;
        int oct = ck8 * 2 + q;
        uint4 v = *reinterpret_cast<const uint4*>(
            slab + (size_t)ck8 * 2048 + xc * 16 + q * 8);
        *reinterpret_cast<uint4*>(&s_h[xc][(oct ^ ((xc >> 2) & 7)) * 8]) = v;
    }
    __syncthreads();

#pragma unroll
    for (int p = 0; p < 16; ++p) {
        int fi = p * 256 + t;
        int ci = fi >> 5, x0 = (fi & 31) * 4;
        const float sg = sig[n * C_ + ci];
        float4 x4 = *reinterpret_cast<const float4*>(
            x + (((size_t)(n * C_ + ci)) * HH + y) * WW + x0);
        float4 v;
        float hv[4];
#pragma unroll
        for (int j = 0; j < 4; ++j) {
            int xr = x0 + j;
            unsigned short hu = s_h[xr][((ci >> 3) ^ ((xr >> 2) & 7)) * 8 + (ci & 7)];
            unsigned int bits = ((unsigned int)hu) << 16;
            hv[j] = *reinterpret_cast<float*>(&bits);
        }
        v.x = hv[0] * sg + x4.x;  v.x = (v.x >= 0.f) ? v.x : a * v.x;
        v.y = hv[1] * sg + x4.y;  v.y = (v.y >= 0.f) ? v.y : a * v.y;
        v.z = hv[2] * sg + x4.z;  v.z = (v.z >= 0.f) ? v.z : a * v.z;
        v.w = hv[3] * sg + x4.w;  v.w = (v.w >= 0.f) ? v.w : a * v.w;
        *reinterpret_cast<float4*>(
            out + (((size_t)(n * C_ + ci)) * HH + y) * WW + x0) = v;
    }
}

// ---------------------------------------------------------------------------
// Fallback epilogue: out = prelu(h * sig[n,c] + x, p2), in-place on d_out.
__global__ __launch_bounds__(256) void epilogue_k(
    const float* __restrict__ x, const float* __restrict__ sig,
    const float* __restrict__ prelu_a, float* __restrict__ out, int total4)
{
    const float a = *prelu_a;
    const int stride = gridDim.x * blockDim.x;
    for (int i = blockIdx.x * blockDim.x + threadIdx.x; i < total4; i += stride) {
        const int nc = (i * 4) >> 14;
        const float s = sig[nc];
        float4 h4 = ((const float4*)out)[i];
        float4 x4 = ((const float4*)x)[i];
        float4 v;
        v.x = h4.x * s + x4.x;  v.x = (v.x >= 0.f) ? v.x : a * v.x;
        v.y = h4.y * s + x4.y;  v.y = (v.y >= 0.f) ? v.y : a * v.y;
        v.z = h4.z * s + x4.z;  v.z = (v.z >= 0.f) ? v.z : a * v.z;
        v.w = h4.w * s + x4.w;  v.w = (v.w >= 0.f) ? v.w : a * v.w;
        ((float4*)out)[i] = v;
    }
}

// ---------------------------------------------------------------------------
extern "C" void kernel_launch(void* const* d_in, const int* in_sizes, int n_in,
                              void* d_out, int out_size, void* d_ws, size_t ws_size,
                              hipStream_t stream)
{
    const float* x         = (const float*)d_in[0];
    const int*   intensity = (const int*)  d_in[1];
    const float* w1        = (const float*)d_in[2];
    const float* b1        = (const float*)d_in[3];
    const float* p1        = (const float*)d_in[4];
    const float* w2        = (const float*)d_in[5];
    const float* b2        = (const float*)d_in[6];
    const float* aW1       = (const float*)d_in[7];
    const float* ab1       = (const float*)d_in[8];
    const float* aW2       = (const float*)d_in[9];
    const float* ab2       = (const float*)d_in[10];
    const float* p2        = (const float*)d_in[11];
    float* out = (float*)d_out;

    const size_t SLAB = (size_t)33554432 * 2;   // 67.1 MB (bf16 tensor)
    const size_t WLB  = (size_t)294912 * 2;     // packed weights bytes
    const size_t NEED = 2 * SLAB + WLB + (size_t)(NN * C_ * NTILES + NN * C_ + 64) * 4;
    const bool big = ws_size >= NEED;

    unsigned short* h1b = (unsigned short*)d_ws;
    unsigned short* xb;       // bf16 ci16-NHWC of x
    unsigned short* h2b = nullptr;
    unsigned short* wl;
    if (big) {
        xb  = (unsigned short*)((char*)d_ws + SLAB);   // aliased: xb then h2b
        h2b = xb;
        wl  = (unsigned short*)((char*)d_ws + 2 * SLAB);
    } else {
        xb  = (unsigned short*)d_out;                  // dead before conv2 writes
        wl  = (unsigned short*)((char*)d_ws + SLAB);
    }
    float* partial = (float*)((char*)wl + WLB);
    float* sig     = partial + (size_t)NN * C_ * NTILES;

    pack_w_k<<<dim3(576), dim3(64), 0, stream>>>(w1, w2, wl);
    to_cnhwc_k<<<dim3(HH, NN), dim3(256), 0, stream>>>(x, xb);

    conv_mfma_k<0><<<dim3(NTILES, 1, NN), dim3(512), 0, stream>>>(
        xb, wl, b1, p1, h1b, nullptr, nullptr);

    if (big) {
        conv_mfma_k<1><<<dim3(NTILES, 1, NN), dim3(512), 0, stream>>>(
            h1b, wl + (size_t)147456, b2, nullptr, h2b, nullptr, partial);
        adapter_k<<<dim3(NN), dim3(C_), 0, stream>>>(
            partial, intensity, aW1, ab1, aW2, ab2, sig);
        epilogue_bf16_k<<<dim3(HH, NN), dim3(256), 0, stream>>>(
            h2b, x, sig, p2, out);
    } else {
        conv_mfma_k<2><<<dim3(NTILES, 1, NN), dim3(512), 0, stream>>>(
            h1b, wl + (size_t)147456, b2, nullptr, nullptr, out, partial);
        adapter_k<<<dim3(NN), dim3(C_), 0, stream>>>(
            partial, intensity, aW1, ab1, aW2, ab2, sig);
        const int total4 = NN * C_ * HH * WW / 4;
        epilogue_k<<<dim3(2048), dim3(256), 0, stream>>>(x, sig, p2, out, total4);
    }
}

// Round 8
// 261.978 us; speedup vs baseline: 1.7465x; 1.1539x over previous
//
#include <hip/hip_runtime.h>
#include <hip/hip_bf16.h>
#include <math.h>

#define NN   16
#define C_   128
#define HH   128
#define WW   128
#define CHID 32
#define NTILES 64     // one tile per output y-pair

typedef short bf16x8 __attribute__((ext_vector_type(8)));
typedef float f32x4  __attribute__((ext_vector_type(4)));

__device__ inline void glds16(const void* g, void* l) {
    __builtin_amdgcn_global_load_lds(
        (const __attribute__((address_space(1))) unsigned int*)g,
        (__attribute__((address_space(3))) unsigned int*)l, 16, 0, 0);
}

__device__ inline unsigned short f2bf(float f) {
    __hip_bfloat16 h = __float2bfloat16(f);
    return *reinterpret_cast<unsigned short*>(&h);
}

// ---------------------------------------------------------------------------
// Pack conv weights into 16x16x32 MFMA-A fragment-linear layout (bf16):
// wl[conv][kk 9][ck 4][cot 8][lane 64][8] ; value = W[co][ci][ky][kx]
// with co = cot*16 + (l&15), ci = ck*32 + (l>>4)*8 + j, kk = ky*3+kx. (R3)
__global__ __launch_bounds__(64) void pack_w_k(
    const float* __restrict__ w1, const float* __restrict__ w2,
    unsigned short* __restrict__ wl)
{
    const int b = blockIdx.x;                 // conv*288 + kk*32 + ck*8 + cot
    const int conv = b / 288, rem = b % 288;
    const int kk = rem / 32, ck = (rem % 32) / 8, cot = rem % 8;
    const int l = threadIdx.x;
    const int co  = cot * 16 + (l & 15);
    const int ci0 = ck * 32 + (l >> 4) * 8;
    const float* W = conv ? w2 : w1;
    union { unsigned short u[8]; uint4 v; } pk;
#pragma unroll
    for (int j = 0; j < 8; ++j)
        pk.u[j] = f2bf(W[(size_t)(co * C_ + ci0 + j) * 9 + kk]);
    unsigned short* dst = wl + (size_t)conv * 147456 +
        ((((size_t)kk * 4 + ck) * 8 + cot) * 64 + l) * 8;
    *reinterpret_cast<uint4*>(dst) = pk.v;
}

// ---------------------------------------------------------------------------
// fp32 NCHW -> bf16 ci16-slab NHWC: xb[n][y][slab 8][px 128][ci16]
// (R7 layout: measured clean 1x writes, unlike the ci32-slab layout.)
__global__ __launch_bounds__(256) void to_cnhwc_k(
    const float* __restrict__ x, unsigned short* __restrict__ xb)
{
    __shared__ unsigned short s_t[128][136];   // row 272B = 17 x 16B slots
    const int y = blockIdx.x, n = blockIdx.y, t = threadIdx.x;

#pragma unroll
    for (int p = 0; p < 16; ++p) {
        int fi = p * 256 + t;                  // float4 index over [ci][x/4]
        int ci = fi >> 5, x0 = (fi & 31) * 4;
        float4 v = *reinterpret_cast<const float4*>(
            x + (((size_t)(n * C_ + ci) * HH) + y) * WW + x0);
        const int slot = ((ci >> 3) ^ ((x0 >> 2) & 7)) * 8 + (ci & 7);
        s_t[x0 + 0][slot] = f2bf(v.x);
        s_t[x0 + 1][slot] = f2bf(v.y);
        s_t[x0 + 2][slot] = f2bf(v.z);
        s_t[x0 + 3][slot] = f2bf(v.w);
    }
    __syncthreads();
    unsigned short* dstbase = xb + ((size_t)(n * HH + y)) * 16384;
#pragma unroll
    for (int p = 0; p < 8; ++p) {
        int o = p * 256 + t;                   // 16B unit: 2048 total
        int sl = o >> 8, u = o & 255;
        int xc = u >> 1, q = u & 1;
        int oct = sl * 2 + q;                  // ci-octet 0..15
        uint4 v = *reinterpret_cast<const uint4*>(
            &s_t[xc][(oct ^ ((xc >> 2) & 7)) * 8]);
        *reinterpret_cast<uint4*>(dstbase + (size_t)sl * 2048 + xc * 16 + q * 8) = v;
    }
}

// ---------------------------------------------------------------------------
// Implicit-GEMM 3x3 conv (R3 compute config). Block: 128co x (2y x 128px).
// 8 waves: wco = w>>2, wy = (w>>1)&1, wxh = w&1 ; wave tile 64co x 64px.
// Single-buffer B tile: 4 rows x 130px x 64B (ci32), slot-swizzled
// s ^ ((xi>>1)&3) -> measured 0 bank conflicts. Staged from ci16-slab global
// layout via linear-dest global_load_lds + per-lane pre-swizzled source.
// Per-block rotated chunk order desynchronizes co-resident blocks.
// MODE 0: bf16 ci16-NHWC out + PReLU (conv1).
// MODE 1: bf16 ci16-NHWC out + avg-pool partials (conv2 big-ws path).
// MODE 2: fp32 NCHW out + partials (conv2 fallback).
template<int MODE>
__global__ __launch_bounds__(512) void conv_mfma_k(
    const unsigned short* __restrict__ inb,   // bf16 ci16-slab NHWC
    const unsigned short* __restrict__ wl,    // this conv's packed frags
    const float* __restrict__ bias,
    const float* __restrict__ prelu_a,
    unsigned short* __restrict__ outb,        // MODE 0/1
    float* __restrict__ outf,                 // MODE 2
    float* __restrict__ partial)              // MODE 1/2
{
    __shared__ char  smem[34816];             // B tile 33792 / repack 34816
    __shared__ float s_part[8][64];

    const int tid = threadIdx.x;
    const int l = tid & 63, w = tid >> 6;
    const int wco = w >> 2, wy = (w >> 1) & 1, wxh = w & 1;
    const int lg = l >> 4, l15 = l & 15;
    const int yp = blockIdx.x, n = blockIdx.z;
    const int y0 = yp * 2;
    const int rot = (yp + n) & 3;

    const f32x4 fz = {0.f, 0.f, 0.f, 0.f};
    f32x4 acc[4][4];
#pragma unroll
    for (int m = 0; m < 4; ++m)
#pragma unroll
        for (int nf = 0; nf < 4; ++nf) acc[m][nf] = fz;

    const bf16x8* wv = reinterpret_cast<const bf16x8*>(wl);
    char* sb = smem;
    const uint4 z4 = {0u, 0u, 0u, 0u};

    // stage ci-chunk ck (32 ci) into the single B buffer
    auto stage = [&](int ck) {
        const int r = w >> 1, xh = w & 1;
        const int ygl = y0 - 1 + r;
        if (ygl < 0 || ygl >= HH) {
            int t2 = xh * 64 + l;
            for (int i = t2; i < 528; i += 128)
                *reinterpret_cast<uint4*>(sb + r * 8448 + i * 16) = z4;
        } else {
            if (xh == 0 && l < 8) {            // zero pad cols xi=0, xi=129
                int col = (l < 4) ? 0 : 129, q = l & 3;
                *reinterpret_cast<uint4*>(sb + r * 8448 + col * 64 + q * 16) = z4;
            }
            const size_t rowbase = ((size_t)(n * HH + ygl)) * 32768;
#pragma unroll
            for (int i = 0; i < 4; ++i) {
                // lane l -> pixel p, LDS slot (l&3); the 16B ci-sub stored at
                // slot s is s ^ f(1+p), f(xi)=(xi>>1)&3 -> pre-swizzle SOURCE.
                const int p  = xh * 64 + i * 16 + (l >> 2);
                const int sd = (l & 3) ^ (((1 + p) >> 1) & 3);
                const char* g = (const char*)inb + rowbase +
                    (size_t)(2 * ck + (sd >> 1)) * 4096 + p * 32 + (sd & 1) * 16;
                glds16(g, sb + r * 8448 + (1 + xh * 64 + i * 16) * 64);
            }
        }
    };

    for (int c8 = 0; c8 < 4; ++c8) {
        const int ck = (c8 + rot) & 3;
        __syncthreads();                       // buf free of previous readers
        stage(ck);
        __syncthreads();                       // staging drained

        // ---- compute: 9 shifted GEMMs; A prefetched one kk ahead ----
        bf16x8 a_cur[4];
#pragma unroll
        for (int m = 0; m < 4; ++m)
            a_cur[m] = wv[(((size_t)0 * 4 + ck) * 8 + wco * 4 + m) * 64 + l];

#pragma unroll
        for (int kk = 0; kk < 9; ++kk) {
            const int ky = kk / 3, kx = kk % 3;
            bf16x8 a_nxt[4];
            if (kk < 8) {
#pragma unroll
                for (int m = 0; m < 4; ++m)
                    a_nxt[m] = wv[((((size_t)kk + 1) * 4 + ck) * 8 + wco * 4 + m) * 64 + l];
            }
            const int rrow = wy + ky;
            bf16x8 b[4];
#pragma unroll
            for (int nf = 0; nf < 4; ++nf) {
                int xi = wxh * 64 + nf * 16 + l15 + kx;
                int slot = lg ^ ((xi >> 1) & 3);
                b[nf] = *reinterpret_cast<const bf16x8*>(
                    sb + rrow * 8448 + xi * 64 + slot * 16);
            }
#pragma unroll
            for (int nf = 0; nf < 4; ++nf)
#pragma unroll
                for (int m = 0; m < 4; ++m)
                    acc[m][nf] = __builtin_amdgcn_mfma_f32_16x16x32_bf16(
                        a_cur[m], b[nf], acc[m][nf], 0, 0, 0);
            if (kk < 8) {
#pragma unroll
                for (int m = 0; m < 4; ++m) a_cur[m] = a_nxt[m];
            }
        }
    }
    __syncthreads();

    // ---- epilogue (16x16 C/D: col px = l15, row co = wco*64+m*16+lg*4+jj) --
    const int ybase = y0 + wy;
    if (MODE == 0 || MODE == 1) {
        const float a1 = (MODE == 0) ? *prelu_a : 0.f;
        float ps[4][4];
        if (MODE == 1) {
#pragma unroll
            for (int m = 0; m < 4; ++m)
#pragma unroll
                for (int jj = 0; jj < 4; ++jj) ps[m][jj] = 0.f;
        }
        unsigned short (*s_rp)[136] = reinterpret_cast<unsigned short (*)[136]>(smem);
        for (int r = 0; r < 2; ++r) {
            if (wy == r) {
#pragma unroll
                for (int m = 0; m < 4; ++m) {
                    const int co0 = wco * 64 + m * 16 + lg * 4;
#pragma unroll
                    for (int nf = 0; nf < 4; ++nf) {
                        const int xc = wxh * 64 + nf * 16 + l15;
                        union { unsigned short u[4]; uint2 v; } pk;
#pragma unroll
                        for (int jj = 0; jj < 4; ++jj) {
                            float f = acc[m][nf][jj] + bias[co0 + jj];
                            if (MODE == 0) f = (f >= 0.f) ? f : a1 * f;
                            else           ps[m][jj] += f;
                            pk.u[jj] = f2bf(f);
                        }
                        *reinterpret_cast<uint2*>(&s_rp[xc][co0]) = pk.v;
                    }
                }
            }
            __syncthreads();
            const int y = y0 + r;
#pragma unroll
            for (int p = 0; p < 4; ++p) {
                int u = p * 512 + tid;         // 2048 16B units: [xc][k16]
                int xc = u >> 4, k = u & 15;
                uint4 v = *reinterpret_cast<const uint4*>(&s_rp[xc][k * 8]);
                *reinterpret_cast<uint4*>(outb +
                    (((size_t)(n * HH + y)) * 8 + (k >> 1)) * 2048 +
                    xc * 16 + (k & 1) * 8) = v;
            }
            __syncthreads();
        }
        if (MODE == 1) {
#pragma unroll
            for (int m = 0; m < 4; ++m)
#pragma unroll
                for (int jj = 0; jj < 4; ++jj) {
                    float s = ps[m][jj];
                    s += __shfl_xor(s, 1); s += __shfl_xor(s, 2);
                    s += __shfl_xor(s, 4); s += __shfl_xor(s, 8);
                    ps[m][jj] = s;
                }
            if (l15 == 0) {
#pragma unroll
                for (int m = 0; m < 4; ++m)
#pragma unroll
                    for (int jj = 0; jj < 4; ++jj)
                        s_part[w][m * 16 + lg * 4 + jj] = ps[m][jj];
            }
            __syncthreads();
            if (tid < C_) {
                const int half = tid >> 6;
                float s = 0.f;
#pragma unroll
                for (int w2 = 0; w2 < 4; ++w2) s += s_part[half * 4 + w2][tid & 63];
                partial[((size_t)(n * C_ + tid)) * NTILES + yp] = s;
            }
        }
    } else {
        float ps[4][4];
#pragma unroll
        for (int m = 0; m < 4; ++m)
#pragma unroll
            for (int jj = 0; jj < 4; ++jj) ps[m][jj] = 0.f;
#pragma unroll
        for (int m = 0; m < 4; ++m) {
            const int co0 = wco * 64 + m * 16 + lg * 4;
#pragma unroll
            for (int nf = 0; nf < 4; ++nf) {
                const int xc = wxh * 64 + nf * 16 + l15;
#pragma unroll
                for (int jj = 0; jj < 4; ++jj) {
                    float f = acc[m][nf][jj] + bias[co0 + jj];
                    outf[(((size_t)(n * C_ + co0 + jj)) * HH + ybase) * WW + xc] = f;
                    ps[m][jj] += f;
                }
            }
        }
#pragma unroll
        for (int m = 0; m < 4; ++m)
#pragma unroll
            for (int jj = 0; jj < 4; ++jj) {
                float s = ps[m][jj];
                s += __shfl_xor(s, 1); s += __shfl_xor(s, 2);
                s += __shfl_xor(s, 4); s += __shfl_xor(s, 8);
                ps[m][jj] = s;
            }
        if (l15 == 0) {
#pragma unroll
            for (int m = 0; m < 4; ++m)
#pragma unroll
                for (int jj = 0; jj < 4; ++jj)
                    s_part[w][m * 16 + lg * 4 + jj] = ps[m][jj];
        }
        __syncthreads();
        if (tid < C_) {
            const int half = tid >> 6;
            float s = 0.f;
#pragma unroll
            for (int w2 = 0; w2 < 4; ++w2) s += s_part[half * 4 + w2][tid & 63];
            partial[((size_t)(n * C_ + tid)) * NTILES + yp] = s;
        }
    }
}

// ---------------------------------------------------------------------------
// One block per sample: reduce partials -> x1, expert MLP, sigmoid gate.
__global__ __launch_bounds__(C_) void adapter_k(
    const float* __restrict__ partial, const int* __restrict__ intensity,
    const float* __restrict__ aW1, const float* __restrict__ ab1,
    const float* __restrict__ aW2, const float* __restrict__ ab2,
    float* __restrict__ sig)
{
    __shared__ float sx[C_];
    __shared__ float sa[CHID];
    const int n = blockIdx.x, c = threadIdx.x;

    float s = 0.f;
    for (int t = 0; t < NTILES; ++t)
        s += partial[(size_t)(n * C_ + c) * NTILES + t];
    sx[c] = s * (1.f / (float)(HH * WW));
    __syncthreads();

    const int idx = intensity[n] - 1;
    if (c < CHID) {
        float a = ab1[idx * CHID + c];
        const float* wrow = aW1 + (size_t)(idx * CHID + c) * C_;
        for (int k = 0; k < C_; ++k) a = fmaf(wrow[k], sx[k], a);
        sa[c] = fmaxf(a, 0.f);
    }
    __syncthreads();

    float g = ab2[idx * C_ + c];
    const float* w2row = aW2 + (size_t)(idx * C_ + c) * CHID;
#pragma unroll
    for (int k = 0; k < CHID; ++k) g = fmaf(w2row[k], sa[k], g);
    sig[n * C_ + c] = 1.f / (1.f + expf(-g));
}

// ---------------------------------------------------------------------------
// Big-ws epilogue: h (bf16 ci16-NHWC) + x (fp32 NCHW) -> out fp32 NCHW.
// out = prelu(h*sig + x, p2). One block per (y, n).
__global__ __launch_bounds__(256) void epilogue_bf16_k(
    const unsigned short* __restrict__ h2b, const float* __restrict__ x,
    const float* __restrict__ sig, const float* __restrict__ prelu_a,
    float* __restrict__ out)
{
    __shared__ unsigned short s_h[128][136];
    const int y = blockIdx.x, n = blockIdx.y, t = threadIdx.x;
    const float a = *prelu_a;
    const unsigned short* slab = h2b + ((size_t)(n * HH + y)) * 16384;

#pragma unroll
    for (int p = 0; p < 8; ++p) {
        int o = p * 256 + t;
        int sl = o >> 8, u = o & 255;
        int xc = u >> 1, q = u & 1;
        int oct = sl * 2 + q;
        uint4 v = *reinterpret_cast<const uint4*>(
            slab + (size_t)sl * 2048 + xc * 16 + q * 8);
        *reinterpret_cast<uint4*>(&s_h[xc][(oct ^ ((xc >> 2) & 7)) * 8]) = v;
    }
    __syncthreads();

#pragma unroll
    for (int p = 0; p < 16; ++p) {
        int fi = p * 256 + t;
        int ci = fi >> 5, x0 = (fi & 31) * 4;
        const float sg = sig[n * C_ + ci];
        float4 x4 = *reinterpret_cast<const float4*>(
            x + (((size_t)(n * C_ + ci)) * HH + y) * WW + x0);
        float4 v;
        float hv[4];
#pragma unroll
        for (int j = 0; j < 4; ++j) {
            int xr = x0 + j;
            unsigned short hu = s_h[xr][((ci >> 3) ^ ((xr >> 2) & 7)) * 8 + (ci & 7)];
            unsigned int bits = ((unsigned int)hu) << 16;
            hv[j] = *reinterpret_cast<float*>(&bits);
        }
        v.x = hv[0] * sg + x4.x;  v.x = (v.x >= 0.f) ? v.x : a * v.x;
        v.y = hv[1] * sg + x4.y;  v.y = (v.y >= 0.f) ? v.y : a * v.y;
        v.z = hv[2] * sg + x4.z;  v.z = (v.z >= 0.f) ? v.z : a * v.z;
        v.w = hv[3] * sg + x4.w;  v.w = (v.w >= 0.f) ? v.w : a * v.w;
        *reinterpret_cast<float4*>(
            out + (((size_t)(n * C_ + ci)) * HH + y) * WW + x0) = v;
    }
}

// ---------------------------------------------------------------------------
// Fallback epilogue: out = prelu(h * sig[n,c] + x, p2), in-place on d_out.
__global__ __launch_bounds__(256) void epilogue_k(
    const float* __restrict__ x, const float* __restrict__ sig,
    const float* __restrict__ prelu_a, float* __restrict__ out, int total4)
{
    const float a = *prelu_a;
    const int stride = gridDim.x * blockDim.x;
    for (int i = blockIdx.x * blockDim.x + threadIdx.x; i < total4; i += stride) {
        const int nc = (i * 4) >> 14;
        const float s = sig[nc];
        float4 h4 = ((const float4*)out)[i];
        float4 x4 = ((const float4*)x)[i];
        float4 v;
        v.x = h4.x * s + x4.x;  v.x = (v.x >= 0.f) ? v.x : a * v.x;
        v.y = h4.y * s + x4.y;  v.y = (v.y >= 0.f) ? v.y : a * v.y;
        v.z = h4.z * s + x4.z;  v.z = (v.z >= 0.f) ? v.z : a * v.z;
        v.w = h4.w * s + x4.w;  v.w = (v.w >= 0.f) ? v.w : a * v.w;
        ((float4*)out)[i] = v;
    }
}

// ---------------------------------------------------------------------------
extern "C" void kernel_launch(void* const* d_in, const int* in_sizes, int n_in,
                              void* d_out, int out_size, void* d_ws, size_t ws_size,
                              hipStream_t stream)
{
    const float* x         = (const float*)d_in[0];
    const int*   intensity = (const int*)  d_in[1];
    const float* w1        = (const float*)d_in[2];
    const float* b1        = (const float*)d_in[3];
    const float* p1        = (const float*)d_in[4];
    const float* w2        = (const float*)d_in[5];
    const float* b2        = (const float*)d_in[6];
    const float* aW1       = (const float*)d_in[7];
    const float* ab1       = (const float*)d_in[8];
    const float* aW2       = (const float*)d_in[9];
    const float* ab2       = (const float*)d_in[10];
    const float* p2        = (const float*)d_in[11];
    float* out = (float*)d_out;

    const size_t SLAB = (size_t)33554432 * 2;   // 67.1 MB (bf16 tensor)
    const size_t WLB  = (size_t)294912 * 2;     // packed weights bytes
    const size_t NEED = 2 * SLAB + WLB + (size_t)(NN * C_ * NTILES + NN * C_ + 64) * 4;
    const bool big = ws_size >= NEED;

    unsigned short* h1b = (unsigned short*)d_ws;
    unsigned short* xb;       // bf16 ci16-NHWC of x
    unsigned short* h2b = nullptr;
    unsigned short* wl;
    if (big) {
        xb  = (unsigned short*)((char*)d_ws + SLAB);   // aliased: xb then h2b
        h2b = xb;
        wl  = (unsigned short*)((char*)d_ws + 2 * SLAB);
    } else {
        xb  = (unsigned short*)d_out;                  // dead before conv2 writes
        wl  = (unsigned short*)((char*)d_ws + SLAB);
    }
    float* partial = (float*)((char*)wl + WLB);
    float* sig     = partial + (size_t)NN * C_ * NTILES;

    pack_w_k<<<dim3(576), dim3(64), 0, stream>>>(w1, w2, wl);
    to_cnhwc_k<<<dim3(HH, NN), dim3(256), 0, stream>>>(x, xb);

    conv_mfma_k<0><<<dim3(NTILES, 1, NN), dim3(512), 0, stream>>>(
        xb, wl, b1, p1, h1b, nullptr, nullptr);

    if (big) {
        conv_mfma_k<1><<<dim3(NTILES, 1, NN), dim3(512), 0, stream>>>(
            h1b, wl + (size_t)147456, b2, nullptr, h2b, nullptr, partial);
        adapter_k<<<dim3(NN), dim3(C_), 0, stream>>>(
            partial, intensity, aW1, ab1, aW2, ab2, sig);
        epilogue_bf16_k<<<dim3(HH, NN), dim3(256), 0, stream>>>(
            h2b, x, sig, p2, out);
    } else {
        conv_mfma_k<2><<<dim3(NTILES, 1, NN), dim3(512), 0, stream>>>(
            h1b, wl + (size_t)147456, b2, nullptr, nullptr, out, partial);
        adapter_k<<<dim3(NN), dim3(C_), 0, stream>>>(
            partial, intensity, aW1, ab1, aW2, ab2, sig);
        const int total4 = NN * C_ * HH * WW / 4;
        epilogue_k<<<dim3(2048), dim3(256), 0, stream>>>(x, sig, p2, out, total4);
    }
}